// Round 1
// baseline (280.826 us; speedup 1.0000x reference)
//
#include <hip/hip_runtime.h>
#include <hip/hip_bf16.h>

#define NN   50000
#define NE   160000
#define DDIM 512
#define MPAD 50048          // 391 * 128
#define NB_SCAN 196         // ceil(NN/256)

typedef __attribute__((ext_vector_type(8))) short  short8;
typedef __attribute__((ext_vector_type(8))) unsigned short ushort8;
typedef __attribute__((ext_vector_type(4))) float  f32x4;

__device__ __forceinline__ unsigned short f2bf(float f) {
  union { float f; unsigned u; } v; v.f = f;
  unsigned u = v.u;
  unsigned r = (u + 0x7FFFu + ((u >> 16) & 1u)) >> 16;   // RNE
  return (unsigned short)r;
}
__device__ __forceinline__ float bf2f(unsigned short s) {
  union { unsigned u; float f; } v; v.u = ((unsigned)s) << 16;
  return v.f;
}
__device__ __forceinline__ void unpack8(uint4 v, float* t) {
  t[0] = bf2f(v.x & 0xffff); t[1] = bf2f(v.x >> 16);
  t[2] = bf2f(v.y & 0xffff); t[3] = bf2f(v.y >> 16);
  t[4] = bf2f(v.z & 0xffff); t[5] = bf2f(v.z >> 16);
  t[6] = bf2f(v.w & 0xffff); t[7] = bf2f(v.w >> 16);
}

// ---------------- graph build ----------------
__global__ void k_init(int* cnt) {
  int i = blockIdx.x * 256 + threadIdx.x;
  if (i < NN) cnt[i] = 0;
}

__global__ void k_deg(const int* __restrict__ ei, int* __restrict__ cnt,
                      int* __restrict__ pos) {
  int e = blockIdx.x * 256 + threadIdx.x;
  if (e < NE) {
    int d = ei[NE + e];                 // dst row
    pos[e] = atomicAdd(&cnt[d], 1);
  }
}

__global__ void k_scan1(const int* __restrict__ cnt, int* __restrict__ bsum) {
  __shared__ int sd[256];
  int t = threadIdx.x;
  int i = blockIdx.x * 256 + t;
  sd[t] = (i < NN) ? cnt[i] : 0;
  __syncthreads();
  for (int off = 128; off > 0; off >>= 1) {
    if (t < off) sd[t] += sd[t + off];
    __syncthreads();
  }
  if (t == 0) bsum[blockIdx.x] = sd[0];
}

__global__ void k_scan2(const int* __restrict__ bsum, int* __restrict__ boff,
                        int* __restrict__ rowstart) {
  __shared__ int sd[256];
  int t = threadIdx.x;
  int v = (t < NB_SCAN) ? bsum[t] : 0;
  int x = v;
  sd[t] = x;
  __syncthreads();
  for (int off = 1; off < 256; off <<= 1) {
    int u = (t >= off) ? sd[t - off] : 0;
    __syncthreads();
    x += u; sd[t] = x;
    __syncthreads();
  }
  if (t < NB_SCAN) boff[t] = x - v;     // exclusive
  if (t == 0) rowstart[NN] = NE;
}

__global__ void k_scan3(const int* __restrict__ cnt, const int* __restrict__ boff,
                        int* __restrict__ rowstart) {
  __shared__ int sd[256];
  int t = threadIdx.x;
  int i = blockIdx.x * 256 + t;
  int v = (i < NN) ? cnt[i] : 0;
  int x = v;
  sd[t] = x;
  __syncthreads();
  for (int off = 1; off < 256; off <<= 1) {
    int u = (t >= off) ? sd[t - off] : 0;
    __syncthreads();
    x += u; sd[t] = x;
    __syncthreads();
  }
  if (i < NN) rowstart[i] = boff[blockIdx.x] + x - v;   // exclusive
}

__global__ void k_fill(const int* __restrict__ ei, const float* __restrict__ ea,
                       const int* __restrict__ rowstart, const int* __restrict__ pos,
                       int* __restrict__ csr_src, float* __restrict__ csr_w) {
  int e = blockIdx.x * 256 + threadIdx.x;
  if (e < NE) {
    int d = ei[NE + e];
    int p = rowstart[d] + pos[e];
    csr_src[p] = ei[e];
    csr_w[p]   = ea[e];
  }
}

// dis1 = rsqrt(1 + sum_w in-edges)  (weighted, layer1)
// dis2 = rsqrt(1 + indegree)        (ones,    layer2)
__global__ void k_dis(const int* __restrict__ rowstart, const float* __restrict__ csr_w,
                      float* __restrict__ dis1, float* __restrict__ dis2) {
  int i = blockIdx.x * 256 + threadIdx.x;
  if (i < NN) {
    int p0 = rowstart[i], p1 = rowstart[i + 1];
    float s = 1.0f;
    for (int p = p0; p < p1; ++p) s += csr_w[p];
    dis1[i] = rsqrtf(s);
    dis2[i] = rsqrtf(1.0f + (float)(p1 - p0));
  }
}

// ---------------- conversions ----------------
__global__ void k_cvt_x(const float* __restrict__ x, unsigned short* __restrict__ xb) {
  size_t t = (size_t)blockIdx.x * 256 + threadIdx.x;   // one 8-elem chunk
  ushort8 o;
  if (t * 8 < (size_t)NN * DDIM) {
    const float4* xp = (const float4*)x;
    float4 a = xp[t * 2], b = xp[t * 2 + 1];
    o[0] = f2bf(a.x); o[1] = f2bf(a.y); o[2] = f2bf(a.z); o[3] = f2bf(a.w);
    o[4] = f2bf(b.x); o[5] = f2bf(b.y); o[6] = f2bf(b.z); o[7] = f2bf(b.w);
  } else {
    #pragma unroll
    for (int j = 0; j < 8; ++j) o[j] = 0;              // zero pad rows
  }
  *(ushort8*)(xb + t * 8) = o;
}

// W [k][n] f32 -> Wt [n][k] bf16, both layers in one pass
__global__ void k_cvt_w(const float* __restrict__ W1, const float* __restrict__ W2,
                        unsigned short* __restrict__ Wt1, unsigned short* __restrict__ Wt2) {
  int t = blockIdx.x * 256 + threadIdx.x;              // < 512*512
  int k = t >> 9, n = t & 511;
  Wt1[n * 512 + k] = f2bf(W1[t]);
  Wt2[n * 512 + k] = f2bf(W2[t]);
}

// ---------------- GEMM: C[m][n] = sum_k A[m][k] * B[n][k], bf16 in/out, f32 acc ----
__global__ __launch_bounds__(256) void k_gemm(
    const unsigned short* __restrict__ A,   // [>=brow+128][512] bf16 row-major (M x K)
    const unsigned short* __restrict__ B,   // [512][512] bf16, n-major (N x K)
    unsigned short* __restrict__ C,         // [Mvalid][512] bf16
    int Mvalid)
{
  __shared__ unsigned short As[128 * 32];   // 8 KB
  __shared__ unsigned short Bs[128 * 32];   // 8 KB
  int brow = blockIdx.x * 128;
  int bcol = blockIdx.y * 128;
  int tid  = threadIdx.x;
  int lane = tid & 63;
  int wave = tid >> 6;
  int wr = wave >> 1, wc = wave & 1;        // 2x2 waves -> 64x64 each
  int r16 = lane & 15, k8 = (lane >> 4) * 8;

  const f32x4 zero = {0.f, 0.f, 0.f, 0.f};
  f32x4 acc[4][4];
  #pragma unroll
  for (int m = 0; m < 4; ++m)
    #pragma unroll
    for (int n = 0; n < 4; ++n) acc[m][n] = zero;

  for (int kt = 0; kt < 512; kt += 32) {
    #pragma unroll
    for (int c = tid; c < 512; c += 256) {  // 512 chunks of 16B per tile
      int row = c >> 2;
      int o8  = (c & 3) << 3;
      uint4 va = *(const uint4*)(A + (size_t)(brow + row) * 512 + kt + o8);
      uint4 vb = *(const uint4*)(B + (size_t)(bcol + row) * 512 + kt + o8);
      *(uint4*)(&As[row * 32 + o8]) = va;
      *(uint4*)(&Bs[row * 32 + o8]) = vb;
    }
    __syncthreads();
    short8 af[4], bfr[4];
    #pragma unroll
    for (int m = 0; m < 4; ++m)
      af[m] = *(const short8*)(&As[(wr * 64 + m * 16 + r16) * 32 + k8]);
    #pragma unroll
    for (int n = 0; n < 4; ++n)
      bfr[n] = *(const short8*)(&Bs[(wc * 64 + n * 16 + r16) * 32 + k8]);
    #pragma unroll
    for (int m = 0; m < 4; ++m)
      #pragma unroll
      for (int n = 0; n < 4; ++n)
        acc[m][n] = __builtin_amdgcn_mfma_f32_16x16x32_bf16(af[m], bfr[n], acc[m][n], 0, 0, 0);
    __syncthreads();
  }

  int rbase = (lane >> 4) * 4;   // C/D: col=lane&15, row=(lane>>4)*4+reg
  int ccol  = lane & 15;
  #pragma unroll
  for (int m = 0; m < 4; ++m)
    #pragma unroll
    for (int n = 0; n < 4; ++n)
      #pragma unroll
      for (int i = 0; i < 4; ++i) {
        int grow = brow + wr * 64 + m * 16 + rbase + i;
        if (grow < Mvalid) {
          int gcol = bcol + wc * 64 + n * 16 + ccol;
          C[(size_t)grow * 512 + gcol] = f2bf(acc[m][n][i]);
        }
      }
}

// ---------------- aggregation: out[i] = b + dis_i^2*h[i] + sum_e dis_s*w*dis_i*h[s] ----
// one wave per node; lane owns dims [lane*8, lane*8+8)
__global__ __launch_bounds__(256) void k_agg(
    const unsigned short* __restrict__ h, const float* __restrict__ dis,
    const float* __restrict__ bias, const int* __restrict__ rowstart,
    const int* __restrict__ csr_src, const float* __restrict__ csr_w,
    int useW, void* __restrict__ outp, int outBf16, int nrows)
{
  int node = blockIdx.x * 4 + (threadIdx.x >> 6);
  int lane = threadIdx.x & 63;
  if (node >= nrows) return;
  if (node >= NN) {                        // pad row (layer-1 bf16 output only)
    ((uint4*)outp)[(size_t)node * 64 + lane] = make_uint4(0, 0, 0, 0);
    return;
  }
  const uint4* hp = (const uint4*)h;
  float di = dis[node];
  float t[8], acc[8];
  uint4 hv = hp[(size_t)node * 64 + lane];
  unpack8(hv, t);
  float selfc = di * di;                   // self-loop: dis_i * 1 * dis_i
  #pragma unroll
  for (int j = 0; j < 8; ++j) acc[j] = t[j] * selfc;
  int p0 = rowstart[node], p1 = rowstart[node + 1];
  for (int p = p0; p < p1; ++p) {
    int s = csr_src[p];
    float c = dis[s] * di;
    if (useW) c *= csr_w[p];
    uint4 v = hp[(size_t)s * 64 + lane];
    unpack8(v, t);
    #pragma unroll
    for (int j = 0; j < 8; ++j) acc[j] += c * t[j];
  }
  const float4* bp = (const float4*)bias;
  float4 b0 = bp[lane * 2], b1 = bp[lane * 2 + 1];
  acc[0] += b0.x; acc[1] += b0.y; acc[2] += b0.z; acc[3] += b0.w;
  acc[4] += b1.x; acc[5] += b1.y; acc[6] += b1.z; acc[7] += b1.w;
  if (outBf16) {                           // layer 1: fuse ReLU + bf16 cast
    ushort8 o;
    #pragma unroll
    for (int j = 0; j < 8; ++j) o[j] = f2bf(fmaxf(acc[j], 0.0f));
    *(ushort8*)((unsigned short*)outp + (size_t)node * 512 + lane * 8) = o;
  } else {                                 // layer 2: f32 final output
    float* op = (float*)outp + (size_t)node * 512 + lane * 8;
    *(float4*)op       = make_float4(acc[0], acc[1], acc[2], acc[3]);
    *(float4*)(op + 4) = make_float4(acc[4], acc[5], acc[6], acc[7]);
  }
}

// ---------------- workspace layout ----------------
constexpr size_t al(size_t x) { return (x + 255) & ~(size_t)255; }
constexpr size_t SZ_XB  = (size_t)MPAD * DDIM * 2;   // bf16 x (padded); reused as relu(h1)
constexpr size_t SZ_H   = (size_t)NN   * DDIM * 2;   // bf16 h1; reused as h2
constexpr size_t SZ_WT  = (size_t)DDIM * DDIM * 2;
constexpr size_t O_XB   = 0;
constexpr size_t O_H    = al(O_XB + SZ_XB);
constexpr size_t O_WT1  = al(O_H + SZ_H);
constexpr size_t O_WT2  = al(O_WT1 + SZ_WT);
constexpr size_t O_DIS1 = al(O_WT2 + SZ_WT);
constexpr size_t O_DIS2 = al(O_DIS1 + (size_t)NN * 4);
constexpr size_t O_CNT  = al(O_DIS2 + (size_t)NN * 4);
constexpr size_t O_RS   = al(O_CNT + (size_t)NN * 4);
constexpr size_t O_POS  = al(O_RS + (size_t)(NN + 1) * 4);
constexpr size_t O_CSRS = al(O_POS + (size_t)NE * 4);
constexpr size_t O_CSRW = al(O_CSRS + (size_t)NE * 4);
constexpr size_t O_BSUM = al(O_CSRW + (size_t)NE * 4);
constexpr size_t O_BOFF = al(O_BSUM + (size_t)NB_SCAN * 4);
constexpr size_t WS_NEED = al(O_BOFF + (size_t)NB_SCAN * 4);

extern "C" void kernel_launch(void* const* d_in, const int* in_sizes, int n_in,
                              void* d_out, int out_size, void* d_ws, size_t ws_size,
                              hipStream_t stream) {
  const float* x  = (const float*)d_in[0];
  const int*   ei = (const int*)d_in[1];
  const float* ea = (const float*)d_in[2];
  const float* W1 = (const float*)d_in[3];
  const float* b1 = (const float*)d_in[4];
  const float* W2 = (const float*)d_in[5];
  const float* b2 = (const float*)d_in[6];
  if (ws_size < WS_NEED) return;

  char* ws = (char*)d_ws;
  unsigned short* xb   = (unsigned short*)(ws + O_XB);   // also relu(h1) later
  unsigned short* h    = (unsigned short*)(ws + O_H);    // h1, then h2
  unsigned short* Wt1  = (unsigned short*)(ws + O_WT1);
  unsigned short* Wt2  = (unsigned short*)(ws + O_WT2);
  float* dis1 = (float*)(ws + O_DIS1);
  float* dis2 = (float*)(ws + O_DIS2);
  int*   cnt  = (int*)(ws + O_CNT);
  int*   rs   = (int*)(ws + O_RS);
  int*   pos  = (int*)(ws + O_POS);
  int*   csrs = (int*)(ws + O_CSRS);
  float* csrw = (float*)(ws + O_CSRW);
  int*   bsum = (int*)(ws + O_BSUM);
  int*   boff = (int*)(ws + O_BOFF);

  // graph build
  k_init <<<NB_SCAN, 256, 0, stream>>>(cnt);
  k_deg  <<<(NE + 255) / 256, 256, 0, stream>>>(ei, cnt, pos);
  k_scan1<<<NB_SCAN, 256, 0, stream>>>(cnt, bsum);
  k_scan2<<<1, 256, 0, stream>>>(bsum, boff, rs);
  k_scan3<<<NB_SCAN, 256, 0, stream>>>(cnt, boff, rs);
  k_fill <<<(NE + 255) / 256, 256, 0, stream>>>(ei, ea, rs, pos, csrs, csrw);
  k_dis  <<<NB_SCAN, 256, 0, stream>>>(rs, csrw, dis1, dis2);

  // conversions
  k_cvt_x<<<(MPAD * (DDIM / 8)) / 256, 256, 0, stream>>>(x, xb);
  k_cvt_w<<<(DDIM * DDIM) / 256, 256, 0, stream>>>(W1, W2, Wt1, Wt2);

  dim3 ggrid(MPAD / 128, DDIM / 128);
  // layer 1
  k_gemm<<<ggrid, 256, 0, stream>>>(xb, Wt1, h, NN);
  k_agg <<<MPAD / 4, 256, 0, stream>>>(h, dis1, b1, rs, csrs, csrw,
                                       1, (void*)xb, 1, MPAD);   // relu->bf16 into xb
  // layer 2
  k_gemm<<<ggrid, 256, 0, stream>>>(xb, Wt2, h, NN);
  k_agg <<<(NN + 3) / 4, 256, 0, stream>>>(h, dis2, b2, rs, csrs, csrw,
                                           0, d_out, 0, NN);     // f32 final
}

// Round 2
// 247.400 us; speedup vs baseline: 1.1351x; 1.1351x over previous
//
#include <hip/hip_runtime.h>
#include <hip/hip_bf16.h>

#define NN   50000
#define NE   160000
#define DDIM 512
#define MPAD 50048          // 391 * 128
#define NB_SCAN 196         // ceil(NN/256)

typedef __attribute__((ext_vector_type(8))) short  short8;
typedef __attribute__((ext_vector_type(8))) unsigned short ushort8;
typedef __attribute__((ext_vector_type(4))) float  f32x4;

__device__ __forceinline__ unsigned short f2bf(float f) {
  union { float f; unsigned u; } v; v.f = f;
  unsigned u = v.u;
  unsigned r = (u + 0x7FFFu + ((u >> 16) & 1u)) >> 16;   // RNE
  return (unsigned short)r;
}
__device__ __forceinline__ float bf2f(unsigned short s) {
  union { unsigned u; float f; } v; v.u = ((unsigned)s) << 16;
  return v.f;
}
__device__ __forceinline__ void unpack8(uint4 v, float* t) {
  t[0] = bf2f(v.x & 0xffff); t[1] = bf2f(v.x >> 16);
  t[2] = bf2f(v.y & 0xffff); t[3] = bf2f(v.y >> 16);
  t[4] = bf2f(v.z & 0xffff); t[5] = bf2f(v.z >> 16);
  t[6] = bf2f(v.w & 0xffff); t[7] = bf2f(v.w >> 16);
}
__device__ __forceinline__ void gload_lds16(const void* g, void* l) {
  __builtin_amdgcn_global_load_lds(
      (const __attribute__((address_space(1))) unsigned int*)g,
      (__attribute__((address_space(3))) unsigned int*)l, 16, 0, 0);
}

// ---------------- graph build ----------------
__global__ void k_init(int* cnt) {
  int i = blockIdx.x * 256 + threadIdx.x;
  if (i < NN) cnt[i] = 0;
}

__global__ void k_deg(const int* __restrict__ ei, int* __restrict__ cnt,
                      int* __restrict__ pos) {
  int e = blockIdx.x * 256 + threadIdx.x;
  if (e < NE) {
    int d = ei[NE + e];                 // dst row
    pos[e] = atomicAdd(&cnt[d], 1);
  }
}

__global__ void k_scan1(const int* __restrict__ cnt, int* __restrict__ bsum) {
  __shared__ int sd[256];
  int t = threadIdx.x;
  int i = blockIdx.x * 256 + t;
  sd[t] = (i < NN) ? cnt[i] : 0;
  __syncthreads();
  for (int off = 128; off > 0; off >>= 1) {
    if (t < off) sd[t] += sd[t + off];
    __syncthreads();
  }
  if (t == 0) bsum[blockIdx.x] = sd[0];
}

__global__ void k_scan2(const int* __restrict__ bsum, int* __restrict__ boff,
                        int* __restrict__ rowstart) {
  __shared__ int sd[256];
  int t = threadIdx.x;
  int v = (t < NB_SCAN) ? bsum[t] : 0;
  int x = v;
  sd[t] = x;
  __syncthreads();
  for (int off = 1; off < 256; off <<= 1) {
    int u = (t >= off) ? sd[t - off] : 0;
    __syncthreads();
    x += u; sd[t] = x;
    __syncthreads();
  }
  if (t < NB_SCAN) boff[t] = x - v;     // exclusive
  if (t == 0) rowstart[NN] = NE;
}

__global__ void k_scan3(const int* __restrict__ cnt, const int* __restrict__ boff,
                        int* __restrict__ rowstart) {
  __shared__ int sd[256];
  int t = threadIdx.x;
  int i = blockIdx.x * 256 + t;
  int v = (i < NN) ? cnt[i] : 0;
  int x = v;
  sd[t] = x;
  __syncthreads();
  for (int off = 1; off < 256; off <<= 1) {
    int u = (t >= off) ? sd[t - off] : 0;
    __syncthreads();
    x += u; sd[t] = x;
    __syncthreads();
  }
  if (i < NN) rowstart[i] = boff[blockIdx.x] + x - v;   // exclusive
}

__global__ void k_fill(const int* __restrict__ ei, const float* __restrict__ ea,
                       const int* __restrict__ rowstart, const int* __restrict__ pos,
                       int* __restrict__ csr_src, float* __restrict__ csr_w) {
  int e = blockIdx.x * 256 + threadIdx.x;
  if (e < NE) {
    int d = ei[NE + e];
    int p = rowstart[d] + pos[e];
    csr_src[p] = ei[e];
    csr_w[p]   = ea[e];
  }
}

// dis1 = rsqrt(1 + sum_w in-edges)  (weighted, layer1)
// dis2 = rsqrt(1 + indegree)        (ones,    layer2)
__global__ void k_dis(const int* __restrict__ rowstart, const float* __restrict__ csr_w,
                      float* __restrict__ dis1, float* __restrict__ dis2) {
  int i = blockIdx.x * 256 + threadIdx.x;
  if (i < NN) {
    int p0 = rowstart[i], p1 = rowstart[i + 1];
    float s = 1.0f;
    for (int p = p0; p < p1; ++p) s += csr_w[p];
    dis1[i] = rsqrtf(s);
    dis2[i] = rsqrtf(1.0f + (float)(p1 - p0));
  }
}

// ---------------- conversions ----------------
__global__ void k_cvt_x(const float* __restrict__ x, unsigned short* __restrict__ xb) {
  size_t t = (size_t)blockIdx.x * 256 + threadIdx.x;   // one 8-elem chunk
  ushort8 o;
  if (t * 8 < (size_t)NN * DDIM) {
    const float4* xp = (const float4*)x;
    float4 a = xp[t * 2], b = xp[t * 2 + 1];
    o[0] = f2bf(a.x); o[1] = f2bf(a.y); o[2] = f2bf(a.z); o[3] = f2bf(a.w);
    o[4] = f2bf(b.x); o[5] = f2bf(b.y); o[6] = f2bf(b.z); o[7] = f2bf(b.w);
  } else {
    #pragma unroll
    for (int j = 0; j < 8; ++j) o[j] = 0;              // zero pad rows
  }
  *(ushort8*)(xb + t * 8) = o;
}

// W [k][n] f32 -> Wt [n][k] bf16, both layers in one pass
__global__ void k_cvt_w(const float* __restrict__ W1, const float* __restrict__ W2,
                        unsigned short* __restrict__ Wt1, unsigned short* __restrict__ Wt2) {
  int t = blockIdx.x * 256 + threadIdx.x;              // < 512*512
  int k = t >> 9, n = t & 511;
  Wt1[n * 512 + k] = f2bf(W1[t]);
  Wt2[n * 512 + k] = f2bf(W2[t]);
}

// ---------------- GEMM: C[m][n] = sum_k A[m][k] * B[n][k], bf16 in/out, f32 acc ----
// m97-style: global_load_lds width=16 staging, BK=64, XOR-swizzled LDS (rule-21:
// linear LDS dest + inverse-swizzled global source + swizzled ds_read), bijective
// XCD chunking (bcol fastest in logical id -> each XCD owns a contiguous brow range).
__global__ __launch_bounds__(256) void k_gemm(
    const unsigned short* __restrict__ A,   // [>=brow+128][512] bf16 row-major (M x K)
    const unsigned short* __restrict__ B,   // [512][512] bf16, n-major (N x K)
    unsigned short* __restrict__ C,         // [Mvalid][512] bf16
    int Mvalid)
{
  __shared__ unsigned short As[128 * 64];   // 16 KB
  __shared__ unsigned short Bs[128 * 64];   // 16 KB

  // bijective XCD swizzle (m204): nwg = gridDim.x, 8 XCDs
  int nwg  = gridDim.x;
  int orig = blockIdx.x;
  int q = nwg >> 3, r = nwg & 7;
  int xcd = orig & 7, pos = orig >> 3;
  int wgid = (xcd < r ? xcd * (q + 1) : r * (q + 1) + (xcd - r) * q) + pos;
  int bcol = (wgid & 3) * 128;              // N/128 = 4, fastest
  int brow = (wgid >> 2) * 128;

  int tid  = threadIdx.x;
  int lane = tid & 63;
  int wave = tid >> 6;
  int wr = wave >> 1, wc = wave & 1;        // 2x2 waves -> 64x64 each
  int r16 = lane & 15;
  int kl16 = (lane >> 4) * 16;              // byte offset of this lane-group's k8

  const f32x4 zero = {0.f, 0.f, 0.f, 0.f};
  f32x4 acc[4][4];
  #pragma unroll
  for (int m = 0; m < 4; ++m)
    #pragma unroll
    for (int n = 0; n < 4; ++n) acc[m][n] = zero;

  for (int kt = 0; kt < 512; kt += 64) {
    // stage 32 KB: 2048 chunks of 16B, 8 per thread (4 A + 4 B).
    // physical LDS linear in chunk index; global source inverse-swizzled.
    #pragma unroll
    for (int i = 0; i < 4; ++i) {
      int c   = tid + (i << 8);             // 0..1023
      int row = c >> 3;                     // 0..127
      int qo  = ((c & 7) << 4) ^ ((row & 7) << 4);   // logical byte col in [0,128)
      gload_lds16(A + (size_t)(brow + row) * 512 + kt + (qo >> 1),
                  (char*)As + (size_t)c * 16);
      gload_lds16(B + (size_t)(bcol + row) * 512 + kt + (qo >> 1),
                  (char*)Bs + (size_t)c * 16);
    }
    __syncthreads();

    #pragma unroll
    for (int ks = 0; ks < 2; ++ks) {
      short8 af[4], bfr[4];
      int qo = kl16 + ks * 64;              // logical byte col of fragment
      #pragma unroll
      for (int m = 0; m < 4; ++m) {
        int row = wr * 64 + m * 16 + r16;
        af[m] = *(const short8*)((const char*)As + row * 128 + (qo ^ ((row & 7) << 4)));
      }
      #pragma unroll
      for (int n = 0; n < 4; ++n) {
        int row = wc * 64 + n * 16 + r16;
        bfr[n] = *(const short8*)((const char*)Bs + row * 128 + (qo ^ ((row & 7) << 4)));
      }
      #pragma unroll
      for (int m = 0; m < 4; ++m)
        #pragma unroll
        for (int n = 0; n < 4; ++n)
          acc[m][n] = __builtin_amdgcn_mfma_f32_16x16x32_bf16(af[m], bfr[n], acc[m][n], 0, 0, 0);
    }
    __syncthreads();
  }

  int rbase = (lane >> 4) * 4;   // C/D: col=lane&15, row=(lane>>4)*4+reg
  int ccol  = lane & 15;
  #pragma unroll
  for (int m = 0; m < 4; ++m)
    #pragma unroll
    for (int n = 0; n < 4; ++n)
      #pragma unroll
      for (int i = 0; i < 4; ++i) {
        int grow = brow + wr * 64 + m * 16 + rbase + i;
        if (grow < Mvalid) {
          int gcol = bcol + wc * 64 + n * 16 + ccol;
          C[(size_t)grow * 512 + gcol] = f2bf(acc[m][n][i]);
        }
      }
}

// ---------------- aggregation: out[i] = b + dis_i^2*h[i] + sum_e dis_s*w*dis_i*h[s] ----
// one wave per node; lane owns dims [lane*8, lane*8+8)
__global__ __launch_bounds__(256) void k_agg(
    const unsigned short* __restrict__ h, const float* __restrict__ dis,
    const float* __restrict__ bias, const int* __restrict__ rowstart,
    const int* __restrict__ csr_src, const float* __restrict__ csr_w,
    int useW, void* __restrict__ outp, int outBf16, int nrows)
{
  int node = blockIdx.x * 4 + (threadIdx.x >> 6);
  int lane = threadIdx.x & 63;
  if (node >= nrows) return;
  if (node >= NN) {                        // pad row (layer-1 bf16 output only)
    ((uint4*)outp)[(size_t)node * 64 + lane] = make_uint4(0, 0, 0, 0);
    return;
  }
  const uint4* hp = (const uint4*)h;
  float di = dis[node];
  float t[8], acc[8];
  uint4 hv = hp[(size_t)node * 64 + lane];
  unpack8(hv, t);
  float selfc = di * di;                   // self-loop: dis_i * 1 * dis_i
  #pragma unroll
  for (int j = 0; j < 8; ++j) acc[j] = t[j] * selfc;
  int p0 = rowstart[node], p1 = rowstart[node + 1];
  for (int p = p0; p < p1; ++p) {
    int s = csr_src[p];
    float c = dis[s] * di;
    if (useW) c *= csr_w[p];
    uint4 v = hp[(size_t)s * 64 + lane];
    unpack8(v, t);
    #pragma unroll
    for (int j = 0; j < 8; ++j) acc[j] += c * t[j];
  }
  const float4* bp = (const float4*)bias;
  float4 b0 = bp[lane * 2], b1 = bp[lane * 2 + 1];
  acc[0] += b0.x; acc[1] += b0.y; acc[2] += b0.z; acc[3] += b0.w;
  acc[4] += b1.x; acc[5] += b1.y; acc[6] += b1.z; acc[7] += b1.w;
  if (outBf16) {                           // layer 1: fuse ReLU + bf16 cast
    ushort8 o;
    #pragma unroll
    for (int j = 0; j < 8; ++j) o[j] = f2bf(fmaxf(acc[j], 0.0f));
    *(ushort8*)((unsigned short*)outp + (size_t)node * 512 + lane * 8) = o;
  } else {                                 // layer 2: f32 final output
    float* op = (float*)outp + (size_t)node * 512 + lane * 8;
    *(float4*)op       = make_float4(acc[0], acc[1], acc[2], acc[3]);
    *(float4*)(op + 4) = make_float4(acc[4], acc[5], acc[6], acc[7]);
  }
}

// ---------------- workspace layout ----------------
constexpr size_t al(size_t x) { return (x + 255) & ~(size_t)255; }
constexpr size_t SZ_XB  = (size_t)MPAD * DDIM * 2;   // bf16 x (padded); reused as relu(h1)
constexpr size_t SZ_H   = (size_t)NN   * DDIM * 2;   // bf16 h1; reused as h2
constexpr size_t SZ_WT  = (size_t)DDIM * DDIM * 2;
constexpr size_t O_XB   = 0;
constexpr size_t O_H    = al(O_XB + SZ_XB);
constexpr size_t O_WT1  = al(O_H + SZ_H);
constexpr size_t O_WT2  = al(O_WT1 + SZ_WT);
constexpr size_t O_DIS1 = al(O_WT2 + SZ_WT);
constexpr size_t O_DIS2 = al(O_DIS1 + (size_t)NN * 4);
constexpr size_t O_CNT  = al(O_DIS2 + (size_t)NN * 4);
constexpr size_t O_RS   = al(O_CNT + (size_t)NN * 4);
constexpr size_t O_POS  = al(O_RS + (size_t)(NN + 1) * 4);
constexpr size_t O_CSRS = al(O_POS + (size_t)NE * 4);
constexpr size_t O_CSRW = al(O_CSRS + (size_t)NE * 4);
constexpr size_t O_BSUM = al(O_CSRW + (size_t)NE * 4);
constexpr size_t O_BOFF = al(O_BSUM + (size_t)NB_SCAN * 4);
constexpr size_t WS_NEED = al(O_BOFF + (size_t)NB_SCAN * 4);

extern "C" void kernel_launch(void* const* d_in, const int* in_sizes, int n_in,
                              void* d_out, int out_size, void* d_ws, size_t ws_size,
                              hipStream_t stream) {
  const float* x  = (const float*)d_in[0];
  const int*   ei = (const int*)d_in[1];
  const float* ea = (const float*)d_in[2];
  const float* W1 = (const float*)d_in[3];
  const float* b1 = (const float*)d_in[4];
  const float* W2 = (const float*)d_in[5];
  const float* b2 = (const float*)d_in[6];
  if (ws_size < WS_NEED) return;

  char* ws = (char*)d_ws;
  unsigned short* xb   = (unsigned short*)(ws + O_XB);   // also relu(h1) later
  unsigned short* h    = (unsigned short*)(ws + O_H);    // h1, then h2
  unsigned short* Wt1  = (unsigned short*)(ws + O_WT1);
  unsigned short* Wt2  = (unsigned short*)(ws + O_WT2);
  float* dis1 = (float*)(ws + O_DIS1);
  float* dis2 = (float*)(ws + O_DIS2);
  int*   cnt  = (int*)(ws + O_CNT);
  int*   rs   = (int*)(ws + O_RS);
  int*   pos  = (int*)(ws + O_POS);
  int*   csrs = (int*)(ws + O_CSRS);
  float* csrw = (float*)(ws + O_CSRW);
  int*   bsum = (int*)(ws + O_BSUM);
  int*   boff = (int*)(ws + O_BOFF);

  // graph build
  k_init <<<NB_SCAN, 256, 0, stream>>>(cnt);
  k_deg  <<<(NE + 255) / 256, 256, 0, stream>>>(ei, cnt, pos);
  k_scan1<<<NB_SCAN, 256, 0, stream>>>(cnt, bsum);
  k_scan2<<<1, 256, 0, stream>>>(bsum, boff, rs);
  k_scan3<<<NB_SCAN, 256, 0, stream>>>(cnt, boff, rs);
  k_fill <<<(NE + 255) / 256, 256, 0, stream>>>(ei, ea, rs, pos, csrs, csrw);
  k_dis  <<<NB_SCAN, 256, 0, stream>>>(rs, csrw, dis1, dis2);

  // conversions
  k_cvt_x<<<(MPAD * (DDIM / 8)) / 256, 256, 0, stream>>>(x, xb);
  k_cvt_w<<<(DDIM * DDIM) / 256, 256, 0, stream>>>(W1, W2, Wt1, Wt2);

  int ngemm = (MPAD / 128) * (DDIM / 128);   // 1564
  // layer 1
  k_gemm<<<ngemm, 256, 0, stream>>>(xb, Wt1, h, NN);
  k_agg <<<MPAD / 4, 256, 0, stream>>>(h, dis1, b1, rs, csrs, csrw,
                                       1, (void*)xb, 1, MPAD);   // relu->bf16 into xb
  // layer 2
  k_gemm<<<ngemm, 256, 0, stream>>>(xb, Wt2, h, NN);
  k_agg <<<(NN + 3) / 4, 256, 0, stream>>>(h, dis2, b2, rs, csrs, csrw,
                                           0, d_out, 0, NN);     // f32 final
}

// Round 3
// 246.739 us; speedup vs baseline: 1.1381x; 1.0027x over previous
//
#include <hip/hip_runtime.h>
#include <hip/hip_bf16.h>

#define NN   50000
#define NE   160000
#define DDIM 512
#define MPAD 50048          // 391 * 128
#define NB_SCAN 196         // ceil(NN/256)

typedef __attribute__((ext_vector_type(8))) short  short8;
typedef __attribute__((ext_vector_type(8))) unsigned short ushort8;
typedef __attribute__((ext_vector_type(4))) float  f32x4;

__device__ __forceinline__ unsigned short f2bf(float f) {
  union { float f; unsigned u; } v; v.f = f;
  unsigned u = v.u;
  unsigned r = (u + 0x7FFFu + ((u >> 16) & 1u)) >> 16;   // RNE
  return (unsigned short)r;
}
__device__ __forceinline__ float bf2f(unsigned short s) {
  union { unsigned u; float f; } v; v.u = ((unsigned)s) << 16;
  return v.f;
}
__device__ __forceinline__ void unpack8(uint4 v, float* t) {
  t[0] = bf2f(v.x & 0xffff); t[1] = bf2f(v.x >> 16);
  t[2] = bf2f(v.y & 0xffff); t[3] = bf2f(v.y >> 16);
  t[4] = bf2f(v.z & 0xffff); t[5] = bf2f(v.z >> 16);
  t[6] = bf2f(v.w & 0xffff); t[7] = bf2f(v.w >> 16);
}
__device__ __forceinline__ void gload_lds16(const void* g, void* l) {
  __builtin_amdgcn_global_load_lds(
      (const __attribute__((address_space(1))) unsigned int*)g,
      (__attribute__((address_space(3))) unsigned int*)l, 16, 0, 0);
}

// ---------------- graph build ----------------
__global__ void k_init(int* cnt) {
  int i = blockIdx.x * 256 + threadIdx.x;
  if (i < NN) cnt[i] = 0;
}

__global__ void k_deg(const int* __restrict__ ei, int* __restrict__ cnt,
                      int* __restrict__ pos) {
  int e = blockIdx.x * 256 + threadIdx.x;
  if (e < NE) {
    int d = ei[NE + e];                 // dst row
    pos[e] = atomicAdd(&cnt[d], 1);
  }
}

__global__ void k_scan1(const int* __restrict__ cnt, int* __restrict__ bsum) {
  __shared__ int sd[256];
  int t = threadIdx.x;
  int i = blockIdx.x * 256 + t;
  sd[t] = (i < NN) ? cnt[i] : 0;
  __syncthreads();
  for (int off = 128; off > 0; off >>= 1) {
    if (t < off) sd[t] += sd[t + off];
    __syncthreads();
  }
  if (t == 0) bsum[blockIdx.x] = sd[0];
}

__global__ void k_scan2(const int* __restrict__ bsum, int* __restrict__ boff,
                        int* __restrict__ rowstart) {
  __shared__ int sd[256];
  int t = threadIdx.x;
  int v = (t < NB_SCAN) ? bsum[t] : 0;
  int x = v;
  sd[t] = x;
  __syncthreads();
  for (int off = 1; off < 256; off <<= 1) {
    int u = (t >= off) ? sd[t - off] : 0;
    __syncthreads();
    x += u; sd[t] = x;
    __syncthreads();
  }
  if (t < NB_SCAN) boff[t] = x - v;     // exclusive
  if (t == 0) rowstart[NN] = NE;
}

__global__ void k_scan3(const int* __restrict__ cnt, const int* __restrict__ boff,
                        int* __restrict__ rowstart) {
  __shared__ int sd[256];
  int t = threadIdx.x;
  int i = blockIdx.x * 256 + t;
  int v = (i < NN) ? cnt[i] : 0;
  int x = v;
  sd[t] = x;
  __syncthreads();
  for (int off = 1; off < 256; off <<= 1) {
    int u = (t >= off) ? sd[t - off] : 0;
    __syncthreads();
    x += u; sd[t] = x;
    __syncthreads();
  }
  if (i < NN) rowstart[i] = boff[blockIdx.x] + x - v;   // exclusive
}

__global__ void k_fill(const int* __restrict__ ei, const float* __restrict__ ea,
                       const int* __restrict__ rowstart, const int* __restrict__ pos,
                       int* __restrict__ csr_src, float* __restrict__ csr_w) {
  int e = blockIdx.x * 256 + threadIdx.x;
  if (e < NE) {
    int d = ei[NE + e];
    int p = rowstart[d] + pos[e];
    csr_src[p] = ei[e];
    csr_w[p]   = ea[e];
  }
}

// dis1 = rsqrt(1 + sum_w in-edges)  (weighted, layer1)
// dis2 = rsqrt(1 + indegree)        (ones,    layer2)
__global__ void k_dis(const int* __restrict__ rowstart, const float* __restrict__ csr_w,
                      float* __restrict__ dis1, float* __restrict__ dis2) {
  int i = blockIdx.x * 256 + threadIdx.x;
  if (i < NN) {
    int p0 = rowstart[i], p1 = rowstart[i + 1];
    float s = 1.0f;
    for (int p = p0; p < p1; ++p) s += csr_w[p];
    dis1[i] = rsqrtf(s);
    dis2[i] = rsqrtf(1.0f + (float)(p1 - p0));
  }
}

// ---------------- conversions ----------------
__global__ void k_cvt_x(const float* __restrict__ x, unsigned short* __restrict__ xb) {
  size_t t = (size_t)blockIdx.x * 256 + threadIdx.x;   // one 8-elem chunk
  ushort8 o;
  if (t * 8 < (size_t)NN * DDIM) {
    const float4* xp = (const float4*)x;
    float4 a = xp[t * 2], b = xp[t * 2 + 1];
    o[0] = f2bf(a.x); o[1] = f2bf(a.y); o[2] = f2bf(a.z); o[3] = f2bf(a.w);
    o[4] = f2bf(b.x); o[5] = f2bf(b.y); o[6] = f2bf(b.z); o[7] = f2bf(b.w);
  } else {
    #pragma unroll
    for (int j = 0; j < 8; ++j) o[j] = 0;              // zero pad rows
  }
  *(ushort8*)(xb + t * 8) = o;
}

// W [k][n] f32 -> Wt [n][k] bf16, both layers in one pass
__global__ void k_cvt_w(const float* __restrict__ W1, const float* __restrict__ W2,
                        unsigned short* __restrict__ Wt1, unsigned short* __restrict__ Wt2) {
  int t = blockIdx.x * 256 + threadIdx.x;              // < 512*512
  int k = t >> 9, n = t & 511;
  Wt1[n * 512 + k] = f2bf(W1[t]);
  Wt2[n * 512 + k] = f2bf(W2[t]);
}

// ---------------- GEMM: C[m][n] = sum_k A[m][k] * B[n][k], bf16 in/out, f32 acc ----
// 2-phase double-buffered pipeline (T3 minimum form): STAGE(t+1) issued BEFORE
// ds_read+MFMA of tile t, one barrier per K-step. global_load_lds width=16,
// rule-21 XOR swizzle (linear LDS dest + inverse-swizzled global src + swizzled
// ds_read), bijective XCD chunking.
__global__ __launch_bounds__(256) void k_gemm(
    const unsigned short* __restrict__ A,   // [>=brow+128][512] bf16 row-major (M x K)
    const unsigned short* __restrict__ B,   // [512][512] bf16, n-major (N x K)
    unsigned short* __restrict__ C,         // [Mvalid][512] bf16
    int Mvalid)
{
  __shared__ unsigned short As[2][128 * 64];   // 2 x 16 KB
  __shared__ unsigned short Bs[2][128 * 64];   // 2 x 16 KB

  // bijective XCD swizzle (m204): nwg = gridDim.x, 8 XCDs
  int nwg  = gridDim.x;
  int orig = blockIdx.x;
  int q = nwg >> 3, r = nwg & 7;
  int xcd = orig & 7, xpos = orig >> 3;
  int wgid = (xcd < r ? xcd * (q + 1) : r * (q + 1) + (xcd - r) * q) + xpos;
  int bcol = (wgid & 3) * 128;              // N/128 = 4, fastest
  int brow = (wgid >> 2) * 128;

  int tid  = threadIdx.x;
  int lane = tid & 63;
  int wave = tid >> 6;
  int wr = wave >> 1, wc = wave & 1;        // 2x2 waves -> 64x64 each
  int r16 = lane & 15;
  int kl16 = (lane >> 4) * 16;              // byte offset of this lane-group's k8

  const f32x4 zero = {0.f, 0.f, 0.f, 0.f};
  f32x4 acc[4][4];
  #pragma unroll
  for (int m = 0; m < 4; ++m)
    #pragma unroll
    for (int n = 0; n < 4; ++n) acc[m][n] = zero;

#define STAGE(buf, kt)                                                          \
  {                                                                             \
    _Pragma("unroll")                                                           \
    for (int i = 0; i < 4; ++i) {                                               \
      int c   = tid + (i << 8);                                                 \
      int row = c >> 3;                                                         \
      int qo  = ((c & 7) << 4) ^ ((row & 7) << 4);                              \
      gload_lds16(A + (size_t)(brow + row) * 512 + (kt) + (qo >> 1),            \
                  (char*)As[buf] + (size_t)c * 16);                             \
      gload_lds16(B + (size_t)(bcol + row) * 512 + (kt) + (qo >> 1),            \
                  (char*)Bs[buf] + (size_t)c * 16);                             \
    }                                                                           \
  }

  STAGE(0, 0);
  __syncthreads();

  #pragma unroll
  for (int t = 0; t < 8; ++t) {
    const int cur = t & 1;
    if (t < 7) STAGE(cur ^ 1, (t + 1) * 64);
    #pragma unroll
    for (int ks = 0; ks < 2; ++ks) {
      short8 af[4], bfr[4];
      int qo = kl16 + ks * 64;              // logical byte col of fragment
      #pragma unroll
      for (int m = 0; m < 4; ++m) {
        int row = wr * 64 + m * 16 + r16;
        af[m] = *(const short8*)((const char*)As[cur] + row * 128 + (qo ^ ((row & 7) << 4)));
      }
      #pragma unroll
      for (int n = 0; n < 4; ++n) {
        int row = wc * 64 + n * 16 + r16;
        bfr[n] = *(const short8*)((const char*)Bs[cur] + row * 128 + (qo ^ ((row & 7) << 4)));
      }
      #pragma unroll
      for (int m = 0; m < 4; ++m)
        #pragma unroll
        for (int n = 0; n < 4; ++n)
          acc[m][n] = __builtin_amdgcn_mfma_f32_16x16x32_bf16(af[m], bfr[n], acc[m][n], 0, 0, 0);
    }
    __syncthreads();   // drains vmcnt(0): tile t+1 landed; all ds_reads of tile t done
  }
#undef STAGE

  int rbase = (lane >> 4) * 4;   // C/D: col=lane&15, row=(lane>>4)*4+reg
  int ccol  = lane & 15;
  #pragma unroll
  for (int m = 0; m < 4; ++m)
    #pragma unroll
    for (int n = 0; n < 4; ++n)
      #pragma unroll
      for (int i = 0; i < 4; ++i) {
        int grow = brow + wr * 64 + m * 16 + rbase + i;
        if (grow < Mvalid) {
          int gcol = bcol + wc * 64 + n * 16 + ccol;
          C[(size_t)grow * 512 + gcol] = f2bf(acc[m][n][i]);
        }
      }
}

// ---------------- aggregation: out[i] = b + dis_i^2*h[i] + sum_e dis_s*w*dis_i*h[s] ----
// one wave per node; lane owns dims [lane*8, lane*8+8); 2-way edge unroll to
// overlap the dependent idx->gather chains of consecutive edges.
__global__ __launch_bounds__(256) void k_agg(
    const unsigned short* __restrict__ h, const float* __restrict__ dis,
    const float* __restrict__ bias, const int* __restrict__ rowstart,
    const int* __restrict__ csr_src, const float* __restrict__ csr_w,
    int useW, void* __restrict__ outp, int outBf16, int nrows)
{
  int node = blockIdx.x * 4 + (threadIdx.x >> 6);
  int lane = threadIdx.x & 63;
  if (node >= nrows) return;
  if (node >= NN) {                        // pad row (layer-1 bf16 output only)
    ((uint4*)outp)[(size_t)node * 64 + lane] = make_uint4(0, 0, 0, 0);
    return;
  }
  const uint4* hp = (const uint4*)h;
  float di = dis[node];
  float t0[8], t1[8], acc[8];
  uint4 hv = hp[(size_t)node * 64 + lane];
  unpack8(hv, t0);
  float selfc = di * di;                   // self-loop: dis_i * 1 * dis_i
  #pragma unroll
  for (int j = 0; j < 8; ++j) acc[j] = t0[j] * selfc;
  int p0 = rowstart[node], p1 = rowstart[node + 1];
  int p = p0;
  for (; p + 2 <= p1; p += 2) {
    int s0 = csr_src[p], s1 = csr_src[p + 1];
    float c0 = dis[s0] * di, c1 = dis[s1] * di;
    if (useW) { c0 *= csr_w[p]; c1 *= csr_w[p + 1]; }
    uint4 v0 = hp[(size_t)s0 * 64 + lane];
    uint4 v1 = hp[(size_t)s1 * 64 + lane];
    unpack8(v0, t0); unpack8(v1, t1);
    #pragma unroll
    for (int j = 0; j < 8; ++j) acc[j] += c0 * t0[j];
    #pragma unroll
    for (int j = 0; j < 8; ++j) acc[j] += c1 * t1[j];
  }
  if (p < p1) {
    int s = csr_src[p];
    float c = dis[s] * di;
    if (useW) c *= csr_w[p];
    uint4 v = hp[(size_t)s * 64 + lane];
    unpack8(v, t0);
    #pragma unroll
    for (int j = 0; j < 8; ++j) acc[j] += c * t0[j];
  }
  const float4* bp = (const float4*)bias;
  float4 b0 = bp[lane * 2], b1 = bp[lane * 2 + 1];
  acc[0] += b0.x; acc[1] += b0.y; acc[2] += b0.z; acc[3] += b0.w;
  acc[4] += b1.x; acc[5] += b1.y; acc[6] += b1.z; acc[7] += b1.w;
  if (outBf16) {                           // layer 1: fuse ReLU + bf16 cast
    ushort8 o;
    #pragma unroll
    for (int j = 0; j < 8; ++j) o[j] = f2bf(fmaxf(acc[j], 0.0f));
    *(ushort8*)((unsigned short*)outp + (size_t)node * 512 + lane * 8) = o;
  } else {                                 // layer 2: f32 final output
    float* op = (float*)outp + (size_t)node * 512 + lane * 8;
    *(float4*)op       = make_float4(acc[0], acc[1], acc[2], acc[3]);
    *(float4*)(op + 4) = make_float4(acc[4], acc[5], acc[6], acc[7]);
  }
}

// ---------------- workspace layout ----------------
constexpr size_t al(size_t x) { return (x + 255) & ~(size_t)255; }
constexpr size_t SZ_XB  = (size_t)MPAD * DDIM * 2;   // bf16 x (padded); reused as relu(h1)
constexpr size_t SZ_H   = (size_t)NN   * DDIM * 2;   // bf16 h1; reused as h2
constexpr size_t SZ_WT  = (size_t)DDIM * DDIM * 2;
constexpr size_t O_XB   = 0;
constexpr size_t O_H    = al(O_XB + SZ_XB);
constexpr size_t O_WT1  = al(O_H + SZ_H);
constexpr size_t O_WT2  = al(O_WT1 + SZ_WT);
constexpr size_t O_DIS1 = al(O_WT2 + SZ_WT);
constexpr size_t O_DIS2 = al(O_DIS1 + (size_t)NN * 4);
constexpr size_t O_CNT  = al(O_DIS2 + (size_t)NN * 4);
constexpr size_t O_RS   = al(O_CNT + (size_t)NN * 4);
constexpr size_t O_POS  = al(O_RS + (size_t)(NN + 1) * 4);
constexpr size_t O_CSRS = al(O_POS + (size_t)NE * 4);
constexpr size_t O_CSRW = al(O_CSRS + (size_t)NE * 4);
constexpr size_t O_BSUM = al(O_CSRW + (size_t)NE * 4);
constexpr size_t O_BOFF = al(O_BSUM + (size_t)NB_SCAN * 4);
constexpr size_t WS_NEED = al(O_BOFF + (size_t)NB_SCAN * 4);

extern "C" void kernel_launch(void* const* d_in, const int* in_sizes, int n_in,
                              void* d_out, int out_size, void* d_ws, size_t ws_size,
                              hipStream_t stream) {
  const float* x  = (const float*)d_in[0];
  const int*   ei = (const int*)d_in[1];
  const float* ea = (const float*)d_in[2];
  const float* W1 = (const float*)d_in[3];
  const float* b1 = (const float*)d_in[4];
  const float* W2 = (const float*)d_in[5];
  const float* b2 = (const float*)d_in[6];
  if (ws_size < WS_NEED) return;

  char* ws = (char*)d_ws;
  unsigned short* xb   = (unsigned short*)(ws + O_XB);   // also relu(h1) later
  unsigned short* h    = (unsigned short*)(ws + O_H);    // h1, then h2
  unsigned short* Wt1  = (unsigned short*)(ws + O_WT1);
  unsigned short* Wt2  = (unsigned short*)(ws + O_WT2);
  float* dis1 = (float*)(ws + O_DIS1);
  float* dis2 = (float*)(ws + O_DIS2);
  int*   cnt  = (int*)(ws + O_CNT);
  int*   rs   = (int*)(ws + O_RS);
  int*   pos  = (int*)(ws + O_POS);
  int*   csrs = (int*)(ws + O_CSRS);
  float* csrw = (float*)(ws + O_CSRW);
  int*   bsum = (int*)(ws + O_BSUM);
  int*   boff = (int*)(ws + O_BOFF);

  // graph build
  k_init <<<NB_SCAN, 256, 0, stream>>>(cnt);
  k_deg  <<<(NE + 255) / 256, 256, 0, stream>>>(ei, cnt, pos);
  k_scan1<<<NB_SCAN, 256, 0, stream>>>(cnt, bsum);
  k_scan2<<<1, 256, 0, stream>>>(bsum, boff, rs);
  k_scan3<<<NB_SCAN, 256, 0, stream>>>(cnt, boff, rs);
  k_fill <<<(NE + 255) / 256, 256, 0, stream>>>(ei, ea, rs, pos, csrs, csrw);
  k_dis  <<<NB_SCAN, 256, 0, stream>>>(rs, csrw, dis1, dis2);

  // conversions
  k_cvt_x<<<(MPAD * (DDIM / 8)) / 256, 256, 0, stream>>>(x, xb);
  k_cvt_w<<<(DDIM * DDIM) / 256, 256, 0, stream>>>(W1, W2, Wt1, Wt2);

  int ngemm = (MPAD / 128) * (DDIM / 128);   // 1564
  // layer 1
  k_gemm<<<ngemm, 256, 0, stream>>>(xb, Wt1, h, NN);
  k_agg <<<MPAD / 4, 256, 0, stream>>>(h, dis1, b1, rs, csrs, csrw,
                                       1, (void*)xb, 1, MPAD);   // relu->bf16 into xb
  // layer 2
  k_gemm<<<ngemm, 256, 0, stream>>>(xb, Wt2, h, NN);
  k_agg <<<(NN + 3) / 4, 256, 0, stream>>>(h, dis2, b2, rs, csrs, csrw,
                                           0, d_out, 0, NN);     // f32 final
}

// Round 4
// 236.782 us; speedup vs baseline: 1.1860x; 1.0420x over previous
//
#include <hip/hip_runtime.h>
#include <hip/hip_bf16.h>

#define NN   50000
#define NE   160000
#define DDIM 512
#define MPAD 50048          // 391 * 128
#define NB_SCAN 196         // ceil(NN/256)

typedef __attribute__((ext_vector_type(8))) short  short8;
typedef __attribute__((ext_vector_type(8))) unsigned short ushort8;
typedef __attribute__((ext_vector_type(4))) float  f32x4;

__device__ __forceinline__ unsigned short f2bf(float f) {
  union { float f; unsigned u; } v; v.f = f;
  unsigned u = v.u;
  unsigned r = (u + 0x7FFFu + ((u >> 16) & 1u)) >> 16;   // RNE
  return (unsigned short)r;
}
__device__ __forceinline__ float bf2f(unsigned short s) {
  union { unsigned u; float f; } v; v.u = ((unsigned)s) << 16;
  return v.f;
}
__device__ __forceinline__ void unpack8(uint4 v, float* t) {
  t[0] = bf2f(v.x & 0xffff); t[1] = bf2f(v.x >> 16);
  t[2] = bf2f(v.y & 0xffff); t[3] = bf2f(v.y >> 16);
  t[4] = bf2f(v.z & 0xffff); t[5] = bf2f(v.z >> 16);
  t[6] = bf2f(v.w & 0xffff); t[7] = bf2f(v.w >> 16);
}
__device__ __forceinline__ void gload_lds16(const void* g, void* l) {
  __builtin_amdgcn_global_load_lds(
      (const __attribute__((address_space(1))) unsigned int*)g,
      (__attribute__((address_space(3))) unsigned int*)l, 16, 0, 0);
}

// ---------------- graph build ----------------
__global__ void k_init(int* cnt) {
  int i = blockIdx.x * 256 + threadIdx.x;
  if (i < NN) cnt[i] = 0;
}

__global__ void k_deg(const int* __restrict__ ei, int* __restrict__ cnt,
                      int* __restrict__ pos) {
  int e = blockIdx.x * 256 + threadIdx.x;
  if (e < NE) {
    int d = ei[NE + e];                 // dst row
    pos[e] = atomicAdd(&cnt[d], 1);
  }
}

__global__ void k_scan1(const int* __restrict__ cnt, int* __restrict__ bsum) {
  __shared__ int sd[256];
  int t = threadIdx.x;
  int i = blockIdx.x * 256 + t;
  sd[t] = (i < NN) ? cnt[i] : 0;
  __syncthreads();
  for (int off = 128; off > 0; off >>= 1) {
    if (t < off) sd[t] += sd[t + off];
    __syncthreads();
  }
  if (t == 0) bsum[blockIdx.x] = sd[0];
}

__global__ void k_scan2(const int* __restrict__ bsum, int* __restrict__ boff,
                        int* __restrict__ rowstart) {
  __shared__ int sd[256];
  int t = threadIdx.x;
  int v = (t < NB_SCAN) ? bsum[t] : 0;
  int x = v;
  sd[t] = x;
  __syncthreads();
  for (int off = 1; off < 256; off <<= 1) {
    int u = (t >= off) ? sd[t - off] : 0;
    __syncthreads();
    x += u; sd[t] = x;
    __syncthreads();
  }
  if (t < NB_SCAN) boff[t] = x - v;     // exclusive
  if (t == 0) rowstart[NN] = NE;
}

__global__ void k_scan3(const int* __restrict__ cnt, const int* __restrict__ boff,
                        int* __restrict__ rowstart) {
  __shared__ int sd[256];
  int t = threadIdx.x;
  int i = blockIdx.x * 256 + t;
  int v = (i < NN) ? cnt[i] : 0;
  int x = v;
  sd[t] = x;
  __syncthreads();
  for (int off = 1; off < 256; off <<= 1) {
    int u = (t >= off) ? sd[t - off] : 0;
    __syncthreads();
    x += u; sd[t] = x;
    __syncthreads();
  }
  if (i < NN) rowstart[i] = boff[blockIdx.x] + x - v;   // exclusive
}

__global__ void k_fill(const int* __restrict__ ei, const float* __restrict__ ea,
                       const int* __restrict__ rowstart, const int* __restrict__ pos,
                       int* __restrict__ csr_src, float* __restrict__ csr_w) {
  int e = blockIdx.x * 256 + threadIdx.x;
  if (e < NE) {
    int d = ei[NE + e];
    int p = rowstart[d] + pos[e];
    csr_src[p] = ei[e];
    csr_w[p]   = ea[e];
  }
}

// dis1 = rsqrt(1 + sum_w in-edges)  (weighted, layer1)
// dis2 = rsqrt(1 + indegree)        (ones,    layer2)
__global__ void k_dis(const int* __restrict__ rowstart, const float* __restrict__ csr_w,
                      float* __restrict__ dis1, float* __restrict__ dis2) {
  int i = blockIdx.x * 256 + threadIdx.x;
  if (i < NN) {
    int p0 = rowstart[i], p1 = rowstart[i + 1];
    float s = 1.0f;
    for (int p = p0; p < p1; ++p) s += csr_w[p];
    dis1[i] = rsqrtf(s);
    dis2[i] = rsqrtf(1.0f + (float)(p1 - p0));
  }
}

// ---------------- conversions ----------------
__global__ void k_cvt_x(const float* __restrict__ x, unsigned short* __restrict__ xb) {
  size_t t = (size_t)blockIdx.x * 256 + threadIdx.x;   // one 8-elem chunk
  ushort8 o;
  if (t * 8 < (size_t)NN * DDIM) {
    const float4* xp = (const float4*)x;
    float4 a = xp[t * 2], b = xp[t * 2 + 1];
    o[0] = f2bf(a.x); o[1] = f2bf(a.y); o[2] = f2bf(a.z); o[3] = f2bf(a.w);
    o[4] = f2bf(b.x); o[5] = f2bf(b.y); o[6] = f2bf(b.z); o[7] = f2bf(b.w);
  } else {
    #pragma unroll
    for (int j = 0; j < 8; ++j) o[j] = 0;              // zero pad rows
  }
  *(ushort8*)(xb + t * 8) = o;
}

// W [k][n] f32 -> Wt [n][k] bf16, both layers in one pass
__global__ void k_cvt_w(const float* __restrict__ W1, const float* __restrict__ W2,
                        unsigned short* __restrict__ Wt1, unsigned short* __restrict__ Wt2) {
  int t = blockIdx.x * 256 + threadIdx.x;              // < 512*512
  int k = t >> 9, n = t & 511;
  Wt1[n * 512 + k] = f2bf(W1[t]);
  Wt2[n * 512 + k] = f2bf(W2[t]);
}

// ---------------- GEMM: C[m][n] = sum_k A[m][k] * B[n][k], bf16 in/out, f32 acc ----
// Double-buffered with COUNTED vmcnt (T4): tile t+1's global_load_lds stay in
// flight across the barrier; each iter waits only for tile t's 8 loads
// (vmcnt(8)), never draining to 0 inside the loop. Raw s_barrier (no implicit
// drain) + "memory" fences + sched_barrier(0) pin ds_reads below the barrier.
// global_load_lds width=16, rule-21 XOR swizzle, bijective XCD chunking.
__global__ __launch_bounds__(256) void k_gemm(
    const unsigned short* __restrict__ A,   // [>=brow+128][512] bf16 row-major (M x K)
    const unsigned short* __restrict__ B,   // [512][512] bf16, n-major (N x K)
    unsigned short* __restrict__ C,         // [Mvalid][512] bf16
    int Mvalid)
{
  __shared__ unsigned short As[2][128 * 64];   // 2 x 16 KB
  __shared__ unsigned short Bs[2][128 * 64];   // 2 x 16 KB

  // bijective XCD swizzle (m204): nwg = gridDim.x, 8 XCDs
  int nwg  = gridDim.x;
  int orig = blockIdx.x;
  int q = nwg >> 3, r = nwg & 7;
  int xcd = orig & 7, xpos = orig >> 3;
  int wgid = (xcd < r ? xcd * (q + 1) : r * (q + 1) + (xcd - r) * q) + xpos;
  int bcol = (wgid & 3) * 128;              // N/128 = 4, fastest
  int brow = (wgid >> 2) * 128;

  int tid  = threadIdx.x;
  int lane = tid & 63;
  int wave = tid >> 6;
  int wr = wave >> 1, wc = wave & 1;        // 2x2 waves -> 64x64 each
  int r16 = lane & 15;
  int kl16 = (lane >> 4) * 16;              // byte offset of this lane-group's k8

  const f32x4 zero = {0.f, 0.f, 0.f, 0.f};
  f32x4 acc[4][4];
  #pragma unroll
  for (int m = 0; m < 4; ++m)
    #pragma unroll
    for (int n = 0; n < 4; ++n) acc[m][n] = zero;

  // STAGE = 8 wave-level global_load_lds (4 A + 4 B) per wave
#define STAGE(buf, kt)                                                          \
  {                                                                             \
    _Pragma("unroll")                                                           \
    for (int i = 0; i < 4; ++i) {                                               \
      int c   = tid + (i << 8);                                                 \
      int row = c >> 3;                                                         \
      int qo  = ((c & 7) << 4) ^ ((row & 7) << 4);                              \
      gload_lds16(A + (size_t)(brow + row) * 512 + (kt) + (qo >> 1),            \
                  (char*)As[buf] + (size_t)c * 16);                             \
      gload_lds16(B + (size_t)(bcol + row) * 512 + (kt) + (qo >> 1),            \
                  (char*)Bs[buf] + (size_t)c * 16);                             \
    }                                                                           \
  }

  STAGE(0, 0);                               // 8 loads in flight (tile 0)

  #pragma unroll
  for (int t = 0; t < 8; ++t) {
    const int cur = t & 1;
    if (t < 7) {
      STAGE(cur ^ 1, (t + 1) * 64);          // +8 -> 16 in flight
      asm volatile("s_waitcnt vmcnt(8)" ::: "memory");   // wait tile t only
    } else {
      asm volatile("s_waitcnt vmcnt(0)" ::: "memory");   // last tile
    }
    __builtin_amdgcn_s_barrier();            // raw: no implicit drain
    asm volatile("" ::: "memory");           // IR fence: ds_reads stay below
    __builtin_amdgcn_sched_barrier(0);       // MIR fence

    #pragma unroll
    for (int ks = 0; ks < 2; ++ks) {
      short8 af[4], bfr[4];
      int qo = kl16 + ks * 64;              // logical byte col of fragment
      #pragma unroll
      for (int m = 0; m < 4; ++m) {
        int row = wr * 64 + m * 16 + r16;
        af[m] = *(const short8*)((const char*)As[cur] + row * 128 + (qo ^ ((row & 7) << 4)));
      }
      #pragma unroll
      for (int n = 0; n < 4; ++n) {
        int row = wc * 64 + n * 16 + r16;
        bfr[n] = *(const short8*)((const char*)Bs[cur] + row * 128 + (qo ^ ((row & 7) << 4)));
      }
      #pragma unroll
      for (int m = 0; m < 4; ++m)
        #pragma unroll
        for (int n = 0; n < 4; ++n)
          acc[m][n] = __builtin_amdgcn_mfma_f32_16x16x32_bf16(af[m], bfr[n], acc[m][n], 0, 0, 0);
    }
    // all ds_reads of buf[cur] completed (MFMA operand dependency) before here;
    // barrier makes that true for every wave before buf[cur] is restaged.
    asm volatile("" ::: "memory");
    __builtin_amdgcn_s_barrier();
  }
#undef STAGE

  int rbase = (lane >> 4) * 4;   // C/D: col=lane&15, row=(lane>>4)*4+reg
  int ccol  = lane & 15;
  #pragma unroll
  for (int m = 0; m < 4; ++m)
    #pragma unroll
    for (int n = 0; n < 4; ++n)
      #pragma unroll
      for (int i = 0; i < 4; ++i) {
        int grow = brow + wr * 64 + m * 16 + rbase + i;
        if (grow < Mvalid) {
          int gcol = bcol + wc * 64 + n * 16 + ccol;
          C[(size_t)grow * 512 + gcol] = f2bf(acc[m][n][i]);
        }
      }
}

// ---------------- aggregation: out[i] = b + dis_i^2*h[i] + sum_e dis_s*w*dis_i*h[s] ----
// one wave per node; lane owns dims [lane*8, lane*8+8); 2-way edge unroll to
// overlap the dependent idx->gather chains of consecutive edges.
__global__ __launch_bounds__(256) void k_agg(
    const unsigned short* __restrict__ h, const float* __restrict__ dis,
    const float* __restrict__ bias, const int* __restrict__ rowstart,
    const int* __restrict__ csr_src, const float* __restrict__ csr_w,
    int useW, void* __restrict__ outp, int outBf16, int nrows)
{
  int node = blockIdx.x * 4 + (threadIdx.x >> 6);
  int lane = threadIdx.x & 63;
  if (node >= nrows) return;
  if (node >= NN) {                        // pad row (layer-1 bf16 output only)
    ((uint4*)outp)[(size_t)node * 64 + lane] = make_uint4(0, 0, 0, 0);
    return;
  }
  const uint4* hp = (const uint4*)h;
  float di = dis[node];
  float t0[8], t1[8], acc[8];
  uint4 hv = hp[(size_t)node * 64 + lane];
  unpack8(hv, t0);
  float selfc = di * di;                   // self-loop: dis_i * 1 * dis_i
  #pragma unroll
  for (int j = 0; j < 8; ++j) acc[j] = t0[j] * selfc;
  int p0 = rowstart[node], p1 = rowstart[node + 1];
  int p = p0;
  for (; p + 2 <= p1; p += 2) {
    int s0 = csr_src[p], s1 = csr_src[p + 1];
    float c0 = dis[s0] * di, c1 = dis[s1] * di;
    if (useW) { c0 *= csr_w[p]; c1 *= csr_w[p + 1]; }
    uint4 v0 = hp[(size_t)s0 * 64 + lane];
    uint4 v1 = hp[(size_t)s1 * 64 + lane];
    unpack8(v0, t0); unpack8(v1, t1);
    #pragma unroll
    for (int j = 0; j < 8; ++j) acc[j] += c0 * t0[j];
    #pragma unroll
    for (int j = 0; j < 8; ++j) acc[j] += c1 * t1[j];
  }
  if (p < p1) {
    int s = csr_src[p];
    float c = dis[s] * di;
    if (useW) c *= csr_w[p];
    uint4 v = hp[(size_t)s * 64 + lane];
    unpack8(v, t0);
    #pragma unroll
    for (int j = 0; j < 8; ++j) acc[j] += c * t0[j];
  }
  const float4* bp = (const float4*)bias;
  float4 b0 = bp[lane * 2], b1 = bp[lane * 2 + 1];
  acc[0] += b0.x; acc[1] += b0.y; acc[2] += b0.z; acc[3] += b0.w;
  acc[4] += b1.x; acc[5] += b1.y; acc[6] += b1.z; acc[7] += b1.w;
  if (outBf16) {                           // layer 1: fuse ReLU + bf16 cast
    ushort8 o;
    #pragma unroll
    for (int j = 0; j < 8; ++j) o[j] = f2bf(fmaxf(acc[j], 0.0f));
    *(ushort8*)((unsigned short*)outp + (size_t)node * 512 + lane * 8) = o;
  } else {                                 // layer 2: f32 final output
    float* op = (float*)outp + (size_t)node * 512 + lane * 8;
    *(float4*)op       = make_float4(acc[0], acc[1], acc[2], acc[3]);
    *(float4*)(op + 4) = make_float4(acc[4], acc[5], acc[6], acc[7]);
  }
}

// ---------------- workspace layout ----------------
constexpr size_t al(size_t x) { return (x + 255) & ~(size_t)255; }
constexpr size_t SZ_XB  = (size_t)MPAD * DDIM * 2;   // bf16 x (padded); reused as relu(h1)
constexpr size_t SZ_H   = (size_t)NN   * DDIM * 2;   // bf16 h1; reused as h2
constexpr size_t SZ_WT  = (size_t)DDIM * DDIM * 2;
constexpr size_t O_XB   = 0;
constexpr size_t O_H    = al(O_XB + SZ_XB);
constexpr size_t O_WT1  = al(O_H + SZ_H);
constexpr size_t O_WT2  = al(O_WT1 + SZ_WT);
constexpr size_t O_DIS1 = al(O_WT2 + SZ_WT);
constexpr size_t O_DIS2 = al(O_DIS1 + (size_t)NN * 4);
constexpr size_t O_CNT  = al(O_DIS2 + (size_t)NN * 4);
constexpr size_t O_RS   = al(O_CNT + (size_t)NN * 4);
constexpr size_t O_POS  = al(O_RS + (size_t)(NN + 1) * 4);
constexpr size_t O_CSRS = al(O_POS + (size_t)NE * 4);
constexpr size_t O_CSRW = al(O_CSRS + (size_t)NE * 4);
constexpr size_t O_BSUM = al(O_CSRW + (size_t)NE * 4);
constexpr size_t O_BOFF = al(O_BSUM + (size_t)NB_SCAN * 4);
constexpr size_t WS_NEED = al(O_BOFF + (size_t)NB_SCAN * 4);

extern "C" void kernel_launch(void* const* d_in, const int* in_sizes, int n_in,
                              void* d_out, int out_size, void* d_ws, size_t ws_size,
                              hipStream_t stream) {
  const float* x  = (const float*)d_in[0];
  const int*   ei = (const int*)d_in[1];
  const float* ea = (const float*)d_in[2];
  const float* W1 = (const float*)d_in[3];
  const float* b1 = (const float*)d_in[4];
  const float* W2 = (const float*)d_in[5];
  const float* b2 = (const float*)d_in[6];
  if (ws_size < WS_NEED) return;

  char* ws = (char*)d_ws;
  unsigned short* xb   = (unsigned short*)(ws + O_XB);   // also relu(h1) later
  unsigned short* h    = (unsigned short*)(ws + O_H);    // h1, then h2
  unsigned short* Wt1  = (unsigned short*)(ws + O_WT1);
  unsigned short* Wt2  = (unsigned short*)(ws + O_WT2);
  float* dis1 = (float*)(ws + O_DIS1);
  float* dis2 = (float*)(ws + O_DIS2);
  int*   cnt  = (int*)(ws + O_CNT);
  int*   rs   = (int*)(ws + O_RS);
  int*   pos  = (int*)(ws + O_POS);
  int*   csrs = (int*)(ws + O_CSRS);
  float* csrw = (float*)(ws + O_CSRW);
  int*   bsum = (int*)(ws + O_BSUM);
  int*   boff = (int*)(ws + O_BOFF);

  // graph build
  k_init <<<NB_SCAN, 256, 0, stream>>>(cnt);
  k_deg  <<<(NE + 255) / 256, 256, 0, stream>>>(ei, cnt, pos);
  k_scan1<<<NB_SCAN, 256, 0, stream>>>(cnt, bsum);
  k_scan2<<<1, 256, 0, stream>>>(bsum, boff, rs);
  k_scan3<<<NB_SCAN, 256, 0, stream>>>(cnt, boff, rs);
  k_fill <<<(NE + 255) / 256, 256, 0, stream>>>(ei, ea, rs, pos, csrs, csrw);
  k_dis  <<<NB_SCAN, 256, 0, stream>>>(rs, csrw, dis1, dis2);

  // conversions
  k_cvt_x<<<(MPAD * (DDIM / 8)) / 256, 256, 0, stream>>>(x, xb);
  k_cvt_w<<<(DDIM * DDIM) / 256, 256, 0, stream>>>(W1, W2, Wt1, Wt2);

  int ngemm = (MPAD / 128) * (DDIM / 128);   // 1564
  // layer 1
  k_gemm<<<ngemm, 256, 0, stream>>>(xb, Wt1, h, NN);
  k_agg <<<MPAD / 4, 256, 0, stream>>>(h, dis1, b1, rs, csrs, csrw,
                                       1, (void*)xb, 1, MPAD);   // relu->bf16 into xb
  // layer 2
  k_gemm<<<ngemm, 256, 0, stream>>>(xb, Wt2, h, NN);
  k_agg <<<(NN + 3) / 4, 256, 0, stream>>>(h, dis2, b2, rs, csrs, csrw,
                                           0, d_out, 0, NN);     // f32 final
}

// Round 5
// 234.551 us; speedup vs baseline: 1.1973x; 1.0095x over previous
//
#include <hip/hip_runtime.h>
#include <hip/hip_bf16.h>

#define NN   50000
#define NE   160000
#define DDIM 512
#define MPAD 50176          // 196 * 256
#define NB_SCAN 196         // ceil(NN/256)

typedef __attribute__((ext_vector_type(8))) short  short8;
typedef __attribute__((ext_vector_type(8))) unsigned short ushort8;
typedef __attribute__((ext_vector_type(4))) float  f32x4;

__device__ __forceinline__ unsigned short f2bf(float f) {
  union { float f; unsigned u; } v; v.f = f;
  unsigned u = v.u;
  unsigned r = (u + 0x7FFFu + ((u >> 16) & 1u)) >> 16;   // RNE
  return (unsigned short)r;
}
__device__ __forceinline__ float bf2f(unsigned short s) {
  union { unsigned u; float f; } v; v.u = ((unsigned)s) << 16;
  return v.f;
}
__device__ __forceinline__ void unpack8(uint4 v, float* t) {
  t[0] = bf2f(v.x & 0xffff); t[1] = bf2f(v.x >> 16);
  t[2] = bf2f(v.y & 0xffff); t[3] = bf2f(v.y >> 16);
  t[4] = bf2f(v.z & 0xffff); t[5] = bf2f(v.z >> 16);
  t[6] = bf2f(v.w & 0xffff); t[7] = bf2f(v.w >> 16);
}
__device__ __forceinline__ void gload_lds16(const void* g, void* l) {
  __builtin_amdgcn_global_load_lds(
      (const __attribute__((address_space(1))) unsigned int*)g,
      (__attribute__((address_space(3))) unsigned int*)l, 16, 0, 0);
}

// ---------------- graph build ----------------
__global__ void k_init(int* cnt) {
  int i = blockIdx.x * 256 + threadIdx.x;
  if (i < NN) cnt[i] = 0;
}

__global__ void k_deg(const int* __restrict__ ei, int* __restrict__ cnt,
                      int* __restrict__ pos) {
  int e = blockIdx.x * 256 + threadIdx.x;
  if (e < NE) {
    int d = ei[NE + e];                 // dst row
    pos[e] = atomicAdd(&cnt[d], 1);
  }
}

__global__ void k_scan1(const int* __restrict__ cnt, int* __restrict__ bsum) {
  __shared__ int sd[256];
  int t = threadIdx.x;
  int i = blockIdx.x * 256 + t;
  sd[t] = (i < NN) ? cnt[i] : 0;
  __syncthreads();
  for (int off = 128; off > 0; off >>= 1) {
    if (t < off) sd[t] += sd[t + off];
    __syncthreads();
  }
  if (t == 0) bsum[blockIdx.x] = sd[0];
}

__global__ void k_scan2(const int* __restrict__ bsum, int* __restrict__ boff,
                        int* __restrict__ rowstart) {
  __shared__ int sd[256];
  int t = threadIdx.x;
  int v = (t < NB_SCAN) ? bsum[t] : 0;
  int x = v;
  sd[t] = x;
  __syncthreads();
  for (int off = 1; off < 256; off <<= 1) {
    int u = (t >= off) ? sd[t - off] : 0;
    __syncthreads();
    x += u; sd[t] = x;
    __syncthreads();
  }
  if (t < NB_SCAN) boff[t] = x - v;     // exclusive
  if (t == 0) rowstart[NN] = NE;
}

__global__ void k_scan3(const int* __restrict__ cnt, const int* __restrict__ boff,
                        int* __restrict__ rowstart) {
  __shared__ int sd[256];
  int t = threadIdx.x;
  int i = blockIdx.x * 256 + t;
  int v = (i < NN) ? cnt[i] : 0;
  int x = v;
  sd[t] = x;
  __syncthreads();
  for (int off = 1; off < 256; off <<= 1) {
    int u = (t >= off) ? sd[t - off] : 0;
    __syncthreads();
    x += u; sd[t] = x;
    __syncthreads();
  }
  if (i < NN) rowstart[i] = boff[blockIdx.x] + x - v;   // exclusive
}

__global__ void k_fill(const int* __restrict__ ei, const float* __restrict__ ea,
                       const int* __restrict__ rowstart, const int* __restrict__ pos,
                       int* __restrict__ csr_src, float* __restrict__ csr_w) {
  int e = blockIdx.x * 256 + threadIdx.x;
  if (e < NE) {
    int d = ei[NE + e];
    int p = rowstart[d] + pos[e];
    csr_src[p] = ei[e];
    csr_w[p]   = ea[e];
  }
}

// dis1 = rsqrt(1 + sum_w in-edges)  (weighted, layer1)
// dis2 = rsqrt(1 + indegree)        (ones,    layer2)
__global__ void k_dis(const int* __restrict__ rowstart, const float* __restrict__ csr_w,
                      float* __restrict__ dis1, float* __restrict__ dis2) {
  int i = blockIdx.x * 256 + threadIdx.x;
  if (i < NN) {
    int p0 = rowstart[i], p1 = rowstart[i + 1];
    float s = 1.0f;
    for (int p = p0; p < p1; ++p) s += csr_w[p];
    dis1[i] = rsqrtf(s);
    dis2[i] = rsqrtf(1.0f + (float)(p1 - p0));
  }
}

// ---------------- conversions ----------------
__global__ void k_cvt_x(const float* __restrict__ x, unsigned short* __restrict__ xb) {
  size_t t = (size_t)blockIdx.x * 256 + threadIdx.x;   // one 8-elem chunk
  ushort8 o;
  if (t * 8 < (size_t)NN * DDIM) {
    const float4* xp = (const float4*)x;
    float4 a = xp[t * 2], b = xp[t * 2 + 1];
    o[0] = f2bf(a.x); o[1] = f2bf(a.y); o[2] = f2bf(a.z); o[3] = f2bf(a.w);
    o[4] = f2bf(b.x); o[5] = f2bf(b.y); o[6] = f2bf(b.z); o[7] = f2bf(b.w);
  } else {
    #pragma unroll
    for (int j = 0; j < 8; ++j) o[j] = 0;              // zero pad rows
  }
  *(ushort8*)(xb + t * 8) = o;
}

// W [k][n] f32 -> Wt [n][k] bf16, both layers in one pass
__global__ void k_cvt_w(const float* __restrict__ W1, const float* __restrict__ W2,
                        unsigned short* __restrict__ Wt1, unsigned short* __restrict__ Wt2) {
  int t = blockIdx.x * 256 + threadIdx.x;              // < 512*512
  int k = t >> 9, n = t & 511;
  Wt1[n * 512 + k] = f2bf(W1[t]);
  Wt2[n * 512 + k] = f2bf(W2[t]);
}

// ---------------- GEMM: C[m][n] = sum_k A[m][k] * B[n][k], bf16 in/out, f32 acc ----
// BM=BN=256, BK=64, 512 threads = 8 waves (2M x 4N), wave tile 128x64.
// Counted-vmcnt double-buffer (R4-verified sync): tile t+1's global_load_lds
// stay in flight across the barrier (vmcnt(8) waits tile t only). Rule-21 XOR
// swizzle (linear LDS dest + inverse-swizzled global src + swizzled ds_read).
// Bijective XCD chunking; bcol fastest (A-panel L2 reuse within XCD).
__global__ __launch_bounds__(512, 2) void k_gemm(
    const unsigned short* __restrict__ A,   // [>=brow+256][512] bf16 row-major (M x K)
    const unsigned short* __restrict__ B,   // [512][512] bf16, n-major (N x K)
    unsigned short* __restrict__ C,         // [Mvalid][512] bf16
    int Mvalid)
{
  __shared__ unsigned short As[2][256 * 64];   // 2 x 32 KB
  __shared__ unsigned short Bs[2][256 * 64];   // 2 x 32 KB  (total 128 KB)

  // bijective XCD swizzle (m204): nwg = gridDim.x = 392 (divisible by 8)
  int nwg  = gridDim.x;
  int orig = blockIdx.x;
  int q = nwg >> 3, r = nwg & 7;
  int xcd = orig & 7, xpos = orig >> 3;
  int wgid = (xcd < r ? xcd * (q + 1) : r * (q + 1) + (xcd - r) * q) + xpos;
  int bcol = (wgid & 1) * 256;              // N/256 = 2, fastest
  int brow = (wgid >> 1) * 256;

  int tid  = threadIdx.x;
  int lane = tid & 63;
  int wave = tid >> 6;
  int wr = wave >> 2, wc = wave & 3;        // 2x4 waves -> 128x64 each
  int r16 = lane & 15;
  int kl16 = (lane >> 4) * 16;              // byte offset of this lane-group's k8

  const f32x4 zero = {0.f, 0.f, 0.f, 0.f};
  f32x4 acc[8][4];
  #pragma unroll
  for (int m = 0; m < 8; ++m)
    #pragma unroll
    for (int n = 0; n < 4; ++n) acc[m][n] = zero;

  // STAGE = 8 wave-level global_load_lds (4 A + 4 B) per wave.
  // 2048 16B-chunks per 32 KB tile; c = tid + i*512, row = c>>3 in [0,256).
#define STAGE(buf, kt)                                                          \
  {                                                                             \
    _Pragma("unroll")                                                           \
    for (int i = 0; i < 4; ++i) {                                               \
      int c   = tid + (i << 9);                                                 \
      int row = c >> 3;                                                         \
      int qo  = ((c & 7) << 4) ^ ((row & 7) << 4);                              \
      gload_lds16(A + (size_t)(brow + row) * 512 + (kt) + (qo >> 1),            \
                  (char*)As[buf] + (size_t)c * 16);                             \
      gload_lds16(B + (size_t)(bcol + row) * 512 + (kt) + (qo >> 1),            \
                  (char*)Bs[buf] + (size_t)c * 16);                             \
    }                                                                           \
  }

  STAGE(0, 0);                               // 8 loads in flight (tile 0)

  #pragma unroll
  for (int t = 0; t < 8; ++t) {
    const int cur = t & 1;
    if (t < 7) {
      STAGE(cur ^ 1, (t + 1) * 64);          // +8 -> 16 in flight
      asm volatile("s_waitcnt vmcnt(8)" ::: "memory");   // wait tile t only
    } else {
      asm volatile("s_waitcnt vmcnt(0)" ::: "memory");   // last tile
    }
    __builtin_amdgcn_s_barrier();            // raw: no implicit drain
    asm volatile("" ::: "memory");           // IR fence: ds_reads stay below
    __builtin_amdgcn_sched_barrier(0);       // MIR fence

    #pragma unroll
    for (int ks = 0; ks < 2; ++ks) {
      short8 af[8], bfr[4];
      int qo = kl16 + ks * 64;              // logical byte col of fragment
      #pragma unroll
      for (int m = 0; m < 8; ++m) {
        int row = wr * 128 + m * 16 + r16;
        af[m] = *(const short8*)((const char*)As[cur] + row * 128 + (qo ^ ((row & 7) << 4)));
      }
      #pragma unroll
      for (int n = 0; n < 4; ++n) {
        int row = wc * 64 + n * 16 + r16;
        bfr[n] = *(const short8*)((const char*)Bs[cur] + row * 128 + (qo ^ ((row & 7) << 4)));
      }
      #pragma unroll
      for (int m = 0; m < 8; ++m)
        #pragma unroll
        for (int n = 0; n < 4; ++n)
          acc[m][n] = __builtin_amdgcn_mfma_f32_16x16x32_bf16(af[m], bfr[n], acc[m][n], 0, 0, 0);
    }
    // all ds_reads of buf[cur] completed (MFMA operand dependency) before here;
    // barrier makes that true for every wave before buf[cur] is restaged.
    asm volatile("" ::: "memory");
    __builtin_amdgcn_s_barrier();
  }
#undef STAGE

  int rbase = (lane >> 4) * 4;   // C/D: col=lane&15, row=(lane>>4)*4+reg
  int ccol  = lane & 15;
  #pragma unroll
  for (int m = 0; m < 8; ++m)
    #pragma unroll
    for (int n = 0; n < 4; ++n)
      #pragma unroll
      for (int i = 0; i < 4; ++i) {
        int grow = brow + wr * 128 + m * 16 + rbase + i;
        if (grow < Mvalid) {
          int gcol = bcol + wc * 64 + n * 16 + ccol;
          C[(size_t)grow * 512 + gcol] = f2bf(acc[m][n][i]);
        }
      }
}

// ---------------- aggregation: out[i] = b + dis_i^2*h[i] + sum_e dis_s*w*dis_i*h[s] ----
// one wave per node; lane owns dims [lane*8, lane*8+8); 2-way edge unroll to
// overlap the dependent idx->gather chains of consecutive edges.
__global__ __launch_bounds__(256) void k_agg(
    const unsigned short* __restrict__ h, const float* __restrict__ dis,
    const float* __restrict__ bias, const int* __restrict__ rowstart,
    const int* __restrict__ csr_src, const float* __restrict__ csr_w,
    int useW, void* __restrict__ outp, int outBf16, int nrows)
{
  int node = blockIdx.x * 4 + (threadIdx.x >> 6);
  int lane = threadIdx.x & 63;
  if (node >= nrows) return;
  if (node >= NN) {                        // pad row (layer-1 bf16 output only)
    ((uint4*)outp)[(size_t)node * 64 + lane] = make_uint4(0, 0, 0, 0);
    return;
  }
  const uint4* hp = (const uint4*)h;
  float di = dis[node];
  float t0[8], t1[8], acc[8];
  uint4 hv = hp[(size_t)node * 64 + lane];
  unpack8(hv, t0);
  float selfc = di * di;                   // self-loop: dis_i * 1 * dis_i
  #pragma unroll
  for (int j = 0; j < 8; ++j) acc[j] = t0[j] * selfc;
  int p0 = rowstart[node], p1 = rowstart[node + 1];
  int p = p0;
  for (; p + 2 <= p1; p += 2) {
    int s0 = csr_src[p], s1 = csr_src[p + 1];
    float c0 = dis[s0] * di, c1 = dis[s1] * di;
    if (useW) { c0 *= csr_w[p]; c1 *= csr_w[p + 1]; }
    uint4 v0 = hp[(size_t)s0 * 64 + lane];
    uint4 v1 = hp[(size_t)s1 * 64 + lane];
    unpack8(v0, t0); unpack8(v1, t1);
    #pragma unroll
    for (int j = 0; j < 8; ++j) acc[j] += c0 * t0[j];
    #pragma unroll
    for (int j = 0; j < 8; ++j) acc[j] += c1 * t1[j];
  }
  if (p < p1) {
    int s = csr_src[p];
    float c = dis[s] * di;
    if (useW) c *= csr_w[p];
    uint4 v = hp[(size_t)s * 64 + lane];
    unpack8(v, t0);
    #pragma unroll
    for (int j = 0; j < 8; ++j) acc[j] += c * t0[j];
  }
  const float4* bp = (const float4*)bias;
  float4 b0 = bp[lane * 2], b1 = bp[lane * 2 + 1];
  acc[0] += b0.x; acc[1] += b0.y; acc[2] += b0.z; acc[3] += b0.w;
  acc[4] += b1.x; acc[5] += b1.y; acc[6] += b1.z; acc[7] += b1.w;
  if (outBf16) {                           // layer 1: fuse ReLU + bf16 cast
    ushort8 o;
    #pragma unroll
    for (int j = 0; j < 8; ++j) o[j] = f2bf(fmaxf(acc[j], 0.0f));
    *(ushort8*)((unsigned short*)outp + (size_t)node * 512 + lane * 8) = o;
  } else {                                 // layer 2: f32 final output
    float* op = (float*)outp + (size_t)node * 512 + lane * 8;
    *(float4*)op       = make_float4(acc[0], acc[1], acc[2], acc[3]);
    *(float4*)(op + 4) = make_float4(acc[4], acc[5], acc[6], acc[7]);
  }
}

// ---------------- workspace layout ----------------
constexpr size_t al(size_t x) { return (x + 255) & ~(size_t)255; }
constexpr size_t SZ_XB  = (size_t)MPAD * DDIM * 2;   // bf16 x (padded); reused as relu(h1)
constexpr size_t SZ_H   = (size_t)NN   * DDIM * 2;   // bf16 h1; reused as h2
constexpr size_t SZ_WT  = (size_t)DDIM * DDIM * 2;
constexpr size_t O_XB   = 0;
constexpr size_t O_H    = al(O_XB + SZ_XB);
constexpr size_t O_WT1  = al(O_H + SZ_H);
constexpr size_t O_WT2  = al(O_WT1 + SZ_WT);
constexpr size_t O_DIS1 = al(O_WT2 + SZ_WT);
constexpr size_t O_DIS2 = al(O_DIS1 + (size_t)NN * 4);
constexpr size_t O_CNT  = al(O_DIS2 + (size_t)NN * 4);
constexpr size_t O_RS   = al(O_CNT + (size_t)NN * 4);
constexpr size_t O_POS  = al(O_RS + (size_t)(NN + 1) * 4);
constexpr size_t O_CSRS = al(O_POS + (size_t)NE * 4);
constexpr size_t O_CSRW = al(O_CSRS + (size_t)NE * 4);
constexpr size_t O_BSUM = al(O_CSRW + (size_t)NE * 4);
constexpr size_t O_BOFF = al(O_BSUM + (size_t)NB_SCAN * 4);
constexpr size_t WS_NEED = al(O_BOFF + (size_t)NB_SCAN * 4);

extern "C" void kernel_launch(void* const* d_in, const int* in_sizes, int n_in,
                              void* d_out, int out_size, void* d_ws, size_t ws_size,
                              hipStream_t stream) {
  const float* x  = (const float*)d_in[0];
  const int*   ei = (const int*)d_in[1];
  const float* ea = (const float*)d_in[2];
  const float* W1 = (const float*)d_in[3];
  const float* b1 = (const float*)d_in[4];
  const float* W2 = (const float*)d_in[5];
  const float* b2 = (const float*)d_in[6];
  if (ws_size < WS_NEED) return;

  char* ws = (char*)d_ws;
  unsigned short* xb   = (unsigned short*)(ws + O_XB);   // also relu(h1) later
  unsigned short* h    = (unsigned short*)(ws + O_H);    // h1, then h2
  unsigned short* Wt1  = (unsigned short*)(ws + O_WT1);
  unsigned short* Wt2  = (unsigned short*)(ws + O_WT2);
  float* dis1 = (float*)(ws + O_DIS1);
  float* dis2 = (float*)(ws + O_DIS2);
  int*   cnt  = (int*)(ws + O_CNT);
  int*   rs   = (int*)(ws + O_RS);
  int*   pos  = (int*)(ws + O_POS);
  int*   csrs = (int*)(ws + O_CSRS);
  float* csrw = (float*)(ws + O_CSRW);
  int*   bsum = (int*)(ws + O_BSUM);
  int*   boff = (int*)(ws + O_BOFF);

  // graph build
  k_init <<<NB_SCAN, 256, 0, stream>>>(cnt);
  k_deg  <<<(NE + 255) / 256, 256, 0, stream>>>(ei, cnt, pos);
  k_scan1<<<NB_SCAN, 256, 0, stream>>>(cnt, bsum);
  k_scan2<<<1, 256, 0, stream>>>(bsum, boff, rs);
  k_scan3<<<NB_SCAN, 256, 0, stream>>>(cnt, boff, rs);
  k_fill <<<(NE + 255) / 256, 256, 0, stream>>>(ei, ea, rs, pos, csrs, csrw);
  k_dis  <<<NB_SCAN, 256, 0, stream>>>(rs, csrw, dis1, dis2);

  // conversions
  k_cvt_x<<<(MPAD * (DDIM / 8)) / 256, 256, 0, stream>>>(x, xb);
  k_cvt_w<<<(DDIM * DDIM) / 256, 256, 0, stream>>>(W1, W2, Wt1, Wt2);

  int ngemm = (MPAD / 256) * (DDIM / 256);   // 392
  // layer 1
  k_gemm<<<ngemm, 512, 0, stream>>>(xb, Wt1, h, NN);
  k_agg <<<MPAD / 4, 256, 0, stream>>>(h, dis1, b1, rs, csrs, csrw,
                                       1, (void*)xb, 1, MPAD);   // relu->bf16 into xb
  // layer 2
  k_gemm<<<ngemm, 512, 0, stream>>>(xb, Wt2, h, NN);
  k_agg <<<(NN + 3) / 4, 256, 0, stream>>>(h, dis2, b2, rs, csrs, csrw,
                                           0, d_out, 0, NN);     // f32 final
}